// Round 4
// baseline (426.025 us; speedup 1.0000x reference)
//
#include <hip/hip_runtime.h>
#include <math.h>

// ViT encoder block (DeepViT ReAttention), B=4 N=1024 D=768 H=8 hd=96 Hdim=3072
// R4: barrier-light attention. Swapped QK^T (A=K,B=Q) with permuted K rows so
// the per-lane score layout == PV A-frag layout; cross-head mix is lane-local;
// one barrier per 256m. Max-pass dropped (fixed exp2 offset), passA = pure sum.

typedef unsigned short u16;
typedef unsigned int u32;
typedef __bf16 bf16x8 __attribute__((ext_vector_type(8)));
typedef float f32x4 __attribute__((ext_vector_type(4)));

#define EPSV 1e-5f
#define SL2E 0.14724444620253177f   // 96^-0.5 * log2(e), folded into q at conv
#define EXPC -11.541560327111707f   // -8 * log2(e)

__device__ __forceinline__ u16 f2bf(float f) {
  union { float f; u32 u; } v; v.f = f;
  u32 u = v.u + 0x7fffu + ((v.u >> 16) & 1u);
  return (u16)(u >> 16);
}
__device__ __forceinline__ float bf2f(u16 h) {
  union { u32 u; float f; } v; v.u = ((u32)h) << 16; return v.f;
}
__device__ __forceinline__ f32x4 mfma16(bf16x8 a, bf16x8 b, f32x4 c) {
  return __builtin_amdgcn_mfma_f32_16x16x32_bf16(a, b, c, 0, 0, 0);
}
__device__ __forceinline__ void gload16(const void* gp, void* lp) {
  __builtin_amdgcn_global_load_lds(
      (const __attribute__((address_space(1))) u32*)gp,
      (__attribute__((address_space(3))) u32*)lp, 16, 0, 0);
}

// ---------------------------------------------------------------- fp32 -> bf16
__global__ __launch_bounds__(256) void k_f2b(const float* __restrict__ s,
                                             u16* __restrict__ d, int n) {
  int i = blockIdx.x * 256 + threadIdx.x;
  int stride = gridDim.x * 256;
  for (; i < n; i += stride) d[i] = f2bf(s[i]);
}

// ---------------------------------------------------------------- conv 3x3 QKV
__global__ __launch_bounds__(256) void k_conv(const float* __restrict__ x,
    const float* __restrict__ wq, const float* __restrict__ wk, const float* __restrict__ wv,
    u16* __restrict__ qhi, u16* __restrict__ qlo,
    u16* __restrict__ khi, u16* __restrict__ klo,
    float* __restrict__ vb)
{
  __shared__ float patch[768], swq[81], swk[81], swv[81];
  int bid = blockIdx.x;            // b*1024 + n
  int b = bid >> 10, n = bid & 1023;
  int t = threadIdx.x;
  const float* xr = x + (size_t)bid * 768;
  patch[t] = xr[t]; patch[t + 256] = xr[t + 256]; patch[t + 512] = xr[t + 512];
  if (t < 81) { swq[t] = wq[t]; swk[t] = wk[t]; swv[t] = wv[t]; }
  __syncthreads();
  #pragma unroll
  for (int r = 0; r < 3; ++r) {
    int f = t + 256 * r;                       // c*256 + p*16 + q
    int o = f >> 8, rem = f & 255, pp = rem >> 4, qq = rem & 15;
    float aq = 0.f, ak = 0.f, av = 0.f;
    #pragma unroll
    for (int i = 0; i < 3; ++i)
      #pragma unroll
      for (int dp = 0; dp < 3; ++dp) {
        int ip = pp + dp - 1;
        if (ip < 0 || ip > 15) continue;
        #pragma unroll
        for (int dq = 0; dq < 3; ++dq) {
          int iq = qq + dq - 1;
          if (iq < 0 || iq > 15) continue;
          float pv = patch[i * 256 + ip * 16 + iq];
          int wi = ((o * 3 + i) * 3 + dp) * 3 + dq;
          aq += swq[wi] * pv; ak += swk[wi] * pv; av += swv[wi] * pv;
        }
      }
    int h = f / 96, d = f - h * 96;
    size_t oi = ((size_t)(b * 8 + h) * 1024 + n) * 96 + d;
    float aqs = aq * SL2E;           // fold softmax scale + log2e into q
    u16 qh_ = f2bf(aqs); qhi[oi] = qh_; qlo[oi] = f2bf(aqs - bf2f(qh_));
    u16 kh_ = f2bf(ak);  khi[oi] = kh_; klo[oi] = f2bf(ak - bf2f(kh_));
    vb[oi] = av;
  }
}

// ------------------------------- V transpose: [bh][n][d] f32 -> [bh][d][n] bf16
__global__ __launch_bounds__(256) void k_vtr(const float* __restrict__ vb,
                                             u16* __restrict__ vtr)
{
  __shared__ u16 lds[12288];     // [96 d][128 n]
  int bid = blockIdx.x;          // bh*8 + ntile
  int bh = bid >> 3, n0 = (bid & 7) * 128;
  int t = threadIdx.x;
  int n = t >> 1, dh = (t & 1) * 48;
  const float* src = vb + ((size_t)bh * 1024 + n0 + n) * 96 + dh;
  #pragma unroll
  for (int j4 = 0; j4 < 12; ++j4) {
    float4 v = *(const float4*)(src + j4 * 4);
    int d = dh + j4 * 4;
    lds[(d + 0) * 128 + n] = f2bf(v.x);
    lds[(d + 1) * 128 + n] = f2bf(v.y);
    lds[(d + 2) * 128 + n] = f2bf(v.z);
    lds[(d + 3) * 128 + n] = f2bf(v.w);
  }
  __syncthreads();
  #pragma unroll
  for (int j = 0; j < 48; ++j) {
    int flat = t + 256 * j;
    int d = flat >> 7, n2 = flat & 127;
    vtr[((size_t)bh * 96 + d) * 1024 + n0 + n2] = lds[flat];
  }
}

// ---------------- pass A: z[n] partial = sum_m exp2(C + EXPC) over an m-quarter
#define LOADK(KH, KL, M)                                            \
  {                                                                 \
    size_t ko_ = (kbase + (M) + l15) * 96 + (size_t)(lhi * 8);      \
    _Pragma("unroll")                                               \
    for (int kk = 0; kk < 3; ++kk) {                                \
      KH[kk] = *(const bf16x8*)(khi + ko_ + kk * 32);               \
      KL[kk] = *(const bf16x8*)(klo + ko_ + kk * 32);               \
    }                                                               \
  }

__global__ __launch_bounds__(256, 4) void k_passA(
    const u16* __restrict__ qhi, const u16* __restrict__ qlo,
    const u16* __restrict__ khi, const u16* __restrict__ klo,
    float* __restrict__ zp)
{
  int bid = blockIdx.x;          // bh*64 + tile*4 + qtr
  int bh = bid >> 6, rest = bid & 63, tile = rest >> 2, qtr = rest & 3;
  int t = threadIdx.x, lane = t & 63, wv = t >> 6;
  int l15 = lane & 15, lhi = lane >> 4;
  int n0 = tile * 64 + wv * 16;
  size_t qoff = ((size_t)bh * 1024 + n0 + l15) * 96 + lhi * 8;
  bf16x8 qh[3], ql[3];
  #pragma unroll
  for (int kk = 0; kk < 3; ++kk) {
    qh[kk] = *(const bf16x8*)(qhi + qoff + kk * 32);
    ql[kk] = *(const bf16x8*)(qlo + qoff + kk * 32);
  }
  size_t kbase = (size_t)bh * 1024;
  float z[4] = {0.f, 0.f, 0.f, 0.f};
  bf16x8 khA[3], klA[3], khB[3], klB[3];
  int m0 = qtr * 256;
  LOADK(khA, klA, m0)
  for (int it = 0; it < 8; ++it) {
    int mb = m0 + it * 32;
    LOADK(khB, klB, mb + 16)
    {
      f32x4 C = {0.f, 0.f, 0.f, 0.f};
      #pragma unroll
      for (int kk = 0; kk < 3; ++kk) {
        C = mfma16(qh[kk], khA[kk], C);
        C = mfma16(qh[kk], klA[kk], C);
        C = mfma16(ql[kk], khA[kk], C);
      }
      #pragma unroll
      for (int r = 0; r < 4; ++r) z[r] += exp2f(C[r] + EXPC);
    }
    if (it < 7) LOADK(khA, klA, mb + 32)
    {
      f32x4 C = {0.f, 0.f, 0.f, 0.f};
      #pragma unroll
      for (int kk = 0; kk < 3; ++kk) {
        C = mfma16(qh[kk], khB[kk], C);
        C = mfma16(qh[kk], klB[kk], C);
        C = mfma16(ql[kk], khB[kk], C);
      }
      #pragma unroll
      for (int r = 0; r < 4; ++r) z[r] += exp2f(C[r] + EXPC);
    }
  }
  #pragma unroll
  for (int off = 1; off < 16; off <<= 1)
    #pragma unroll
    for (int r = 0; r < 4; ++r) z[r] += __shfl_xor(z[r], off);
  if (l15 == 0) {
    #pragma unroll
    for (int r = 0; r < 4; ++r)
      zp[qtr * 32768 + bh * 1024 + n0 + lhi * 4 + r] = z[r];
  }
}

// --------------------------------------- merge 4 z-quarters -> invZ
__global__ __launch_bounds__(256) void k_zmerge(const float* __restrict__ zp,
                                                float* __restrict__ invZ)
{
  int idx = blockIdx.x * 256 + threadIdx.x;   // < 32768
  float z = zp[idx] + zp[32768 + idx] + zp[65536 + idx] + zp[98304 + idx];
  invZ[idx] = 1.f / z;
}

// ---------------- pass B: per block (b, ntile, mq): phase1 = waves own 32-m
// chunks, compute all-head scores (swapped QK^T, permuted K rows), lane-local
// softmax+mix -> bf16 PV A-frags to LDS; barrier; phase2 = waves own heads,
// PV over the 256-m quarter. One barrier total.
__global__ __launch_bounds__(512, 2) void k_passB(
    const u16* __restrict__ qhi, const u16* __restrict__ qlo,
    const u16* __restrict__ khi, const u16* __restrict__ klo,
    const u16* __restrict__ vtr, const float* __restrict__ invZ,
    const float* __restrict__ rw,
    float* __restrict__ U0, float* __restrict__ U1,
    float* __restrict__ U2, float* __restrict__ U3,
    float* __restrict__ pstat)
{
  __shared__ u16 clds[32768];    // 64KB: [w*8+g][lane] 16B frags
  int bid = blockIdx.x;          // b*256 + nt*4 + mq
  int b = bid >> 8, rest = bid & 255, nt = rest >> 2, mq = rest & 3;
  int n0 = nt * 16;
  int t = threadIdx.x, lane = t & 63, w = t >> 6;
  int l15 = lane & 15, lhi = lane >> 4;
  int mbase = mq * 256 + w * 32;                       // phase-1 m chunk
  int mrow0 = mbase + ((l15 >> 2) * 8) + (l15 & 3);    // permuted K row, tile0

  // per-g mix accumulators, init with analytic centering -sum(W_g)/1024
  float cm[8][8];
  #pragma unroll
  for (int g = 0; g < 8; ++g) {
    float wsum = 0.f;
    #pragma unroll
    for (int h = 0; h < 8; ++h) wsum += rw[g * 8 + h];
    float cg = -wsum * (1.f / 1024.f);
    #pragma unroll
    for (int jj = 0; jj < 8; ++jj) cm[g][jj] = cg;
  }

  for (int h = 0; h < 8; ++h) {
    size_t base = (size_t)(b * 8 + h) * 1024;
    size_t q_off = (base + n0 + l15) * 96 + lhi * 8;
    size_t k_off = (base + mrow0) * 96 + lhi * 8;
    bf16x8 qh8[3], ql8[3], kh0[3], kl0[3], kh1[3], kl1[3];
    #pragma unroll
    for (int kk = 0; kk < 3; ++kk) {
      kh0[kk] = *(const bf16x8*)(khi + k_off + kk * 32);
      kl0[kk] = *(const bf16x8*)(klo + k_off + kk * 32);
      kh1[kk] = *(const bf16x8*)(khi + k_off + 384 + kk * 32);  // +4 rows
      kl1[kk] = *(const bf16x8*)(klo + k_off + 384 + kk * 32);
      qh8[kk] = *(const bf16x8*)(qhi + q_off + kk * 32);
      ql8[kk] = *(const bf16x8*)(qlo + q_off + kk * 32);
    }
    f32x4 C0 = {0.f, 0.f, 0.f, 0.f}, C1 = {0.f, 0.f, 0.f, 0.f};
    #pragma unroll
    for (int kk = 0; kk < 3; ++kk) {
      C0 = mfma16(kh0[kk], qh8[kk], C0);   // q_hi*k_hi
      C0 = mfma16(kl0[kk], qh8[kk], C0);   // q_hi*k_lo
      C0 = mfma16(kh0[kk], ql8[kk], C0);   // q_lo*k_hi
      C1 = mfma16(kh1[kk], qh8[kk], C1);
      C1 = mfma16(kl1[kk], qh8[kk], C1);
      C1 = mfma16(kh1[kk], ql8[kk], C1);
    }
    float iz = invZ[base + n0 + l15];
    #pragma unroll
    for (int r = 0; r < 4; ++r) {
      float p0 = exp2f(C0[r] + EXPC) * iz;   // m-off = lhi*8 + r
      float p1 = exp2f(C1[r] + EXPC) * iz;   // m-off = lhi*8 + 4 + r
      #pragma unroll
      for (int g = 0; g < 8; ++g) {
        float wgh = rw[g * 8 + h];
        cm[g][r]     += wgh * p0;
        cm[g][4 + r] += wgh * p1;
      }
    }
  }

  // BN stats (per g, this wave's (16n x 32m) patch)
  {
    float sc[8], scc[8];
    #pragma unroll
    for (int g = 0; g < 8; ++g) {
      float s = 0.f, ss = 0.f;
      #pragma unroll
      for (int jj = 0; jj < 8; ++jj) { float v = cm[g][jj]; s += v; ss += v * v; }
      sc[g] = s; scc[g] = ss;
    }
    #pragma unroll
    for (int off = 32; off > 0; off >>= 1)
      #pragma unroll
      for (int g = 0; g < 8; ++g) {
        sc[g] += __shfl_down(sc[g], off);
        scc[g] += __shfl_down(scc[g], off);
      }
    if (lane == 0) {
      #pragma unroll
      for (int g = 0; g < 8; ++g) {
        pstat[(size_t)(bid * 8 + w) * 16 + g] = sc[g];
        pstat[(size_t)(bid * 8 + w) * 16 + 8 + g] = scc[g];
      }
    }
  }

  // pack + stash PV A-frags
  #pragma unroll
  for (int g = 0; g < 8; ++g) {
    union { u16 us[8]; bf16x8 bv; } pk;
    #pragma unroll
    for (int jj = 0; jj < 8; ++jj) pk.us[jj] = f2bf(cm[g][jj]);
    *(bf16x8*)&clds[((w * 8 + g) * 64 + lane) * 8] = pk.bv;
  }
  __syncthreads();

  // phase 2: wave w = head w, PV over all 8 m-chunks of this quarter
  f32x4 acc[6];
  #pragma unroll
  for (int ds = 0; ds < 6; ++ds) acc[ds] = (f32x4){0.f, 0.f, 0.f, 0.f};
  size_t vbase = (size_t)(b * 8 + w) * 96;
  for (int mc = 0; mc < 8; ++mc) {
    bf16x8 af = *(const bf16x8*)&clds[((mc * 8 + w) * 64 + lane) * 8];
    int mof = mq * 256 + mc * 32 + lhi * 8;
    #pragma unroll
    for (int ds = 0; ds < 6; ++ds) {
      bf16x8 vf = *(const bf16x8*)(vtr + (vbase + ds * 16 + l15) * 1024 + mof);
      acc[ds] = mfma16(af, vf, acc[ds]);
    }
  }
  float* Uq = (mq == 0) ? U0 : (mq == 1) ? U1 : (mq == 2) ? U2 : U3;
  #pragma unroll
  for (int ds = 0; ds < 6; ++ds)
    #pragma unroll
    for (int r = 0; r < 4; ++r) {
      int n = lhi * 4 + r;
      Uq[((size_t)(b * 1024 + n0 + n)) * 768 + w * 96 + ds * 16 + l15] = acc[ds][r];
    }
}

// ------------------------------------------------- colsum(V) per (b,h,d), fp32
__global__ __launch_bounds__(384) void k_vcs(const float* __restrict__ vb,
                                             float* __restrict__ vcs)
{
  __shared__ float part[4][96];
  int bh = blockIdx.x, t = threadIdx.x;
  int c = t % 96, g4 = t / 96;
  float a = 0.f;
  const float* vp = vb + (size_t)bh * 98304 + (size_t)g4 * 24576 + c;
  for (int m = 0; m < 256; ++m) a += vp[m * 96];
  part[g4][c] = a;
  __syncthreads();
  if (t < 96) vcs[bh * 96 + t] = part[0][t] + part[1][t] + part[2][t] + part[3][t];
}

// ------------------------------------------------- BN partial reduce (8192x16)
__global__ __launch_bounds__(256) void k_statred(const float* __restrict__ pstat,
                                                 float* __restrict__ stats)
{
  __shared__ float part[16][17];
  int t = threadIdx.x;
  int j = t >> 4, s = t & 15;
  float a = 0.f;
  for (int k2 = 0; k2 < 512; ++k2) a += pstat[(size_t)(s + 16 * k2) * 16 + j];
  part[j][s] = a;
  __syncthreads();
  if (t < 16) {
    float v = 0.f;
    for (int s2 = 0; s2 < 16; ++s2) v += part[t][s2];
    stats[t] = v;
  }
}

// ------------- BN affine: ubb = bf16(sg*(U0+U1+U2+U3) + (bnb - sg*mc)*colsum(V))
__global__ __launch_bounds__(256) void k_bnfin(const float* __restrict__ U0,
    const float* __restrict__ U1, const float* __restrict__ U2,
    const float* __restrict__ U3, const float* __restrict__ vcs,
    const float* __restrict__ stats, const float* __restrict__ bng,
    const float* __restrict__ bnb, u16* __restrict__ ubb)
{
  size_t idx = (size_t)blockIdx.x * 256 + threadIdx.x;
  int col = (int)(idx % 768); int i = (int)(idx / 768); int b = i >> 10;
  int g = col / 96, d = col - g * 96;
  const float cnt = 4194304.f;  // B*N*N
  float mc = stats[g] / cnt;
  float var = stats[8 + g] / cnt - mc * mc;
  float sg = bng[g] * rsqrtf(var + EPSV);
  float tg = bnb[g] - sg * mc;
  float u = (U0[idx] + U1[idx]) + (U2[idx] + U3[idx]);
  ubb[idx] = f2bf(sg * u + tg * vcs[(b * 8 + g) * 96 + d]);
}

// -------- bf16 MFMA GEMM: out = A[M,K]@W[N,K]^T + bias (+res)(+gelu)(+LN stats)
template<int GELU_, int RES_, int STATS_, int BF16OUT>
__global__ __launch_bounds__(256) void k_gemm(
    const u16* __restrict__ A, const u16* __restrict__ W,
    const float* __restrict__ bias, const float* __restrict__ res,
    float* __restrict__ out, u16* __restrict__ outb,
    int K, int Nc, float* __restrict__ stats)
{
  __shared__ u16 As[8192], Bs[8192];   // 128 rows x 64 cols, XOR-swizzled
  __shared__ float red[8];
  int t = threadIdx.x, lane = t & 63, wv = t >> 6;
  int l15 = lane & 15, lhi = lane >> 4;
  int i0 = blockIdx.y * 128, j0 = blockIdx.x * 128;
  int wr = wv >> 1, wc = wv & 1;
  f32x4 acc[4][4];
  #pragma unroll
  for (int mi = 0; mi < 4; ++mi)
    #pragma unroll
    for (int ni = 0; ni < 4; ++ni) acc[mi][ni] = (f32x4){0.f, 0.f, 0.f, 0.f};
  int rA = lane >> 3;
  int colel = 8 * ((lane & 7) ^ rA);   // pre-swizzled global source column
  for (int k0 = 0; k0 < K; k0 += 64) {
    if (k0) __syncthreads();
    #pragma unroll
    for (int i = 0; i < 4; ++i) {
      int cA = wv * 4 + i;
      int r = cA * 8 + rA;
      gload16(A + (size_t)(i0 + r) * K + k0 + colel, &As[cA * 512]);
      gload16(W + (size_t)(j0 + r) * K + k0 + colel, &Bs[cA * 512]);
    }
    __syncthreads();
    #pragma unroll
    for (int ks = 0; ks < 2; ++ks) {
      bf16x8 af[4], bf[4];
      #pragma unroll
      for (int mi = 0; mi < 4; ++mi) {
        int r2 = wr * 64 + mi * 16 + l15;
        af[mi] = *(const bf16x8*)&As[r2 * 64 + ((ks * 32 + lhi * 8) ^ (8 * (r2 & 7)))];
      }
      #pragma unroll
      for (int ni = 0; ni < 4; ++ni) {
        int r3 = wc * 64 + ni * 16 + l15;
        bf[ni] = *(const bf16x8*)&Bs[r3 * 64 + ((ks * 32 + lhi * 8) ^ (8 * (r3 & 7)))];
      }
      #pragma unroll
      for (int mi = 0; mi < 4; ++mi)
        #pragma unroll
        for (int ni = 0; ni < 4; ++ni)
          acc[mi][ni] = mfma16(af[mi], bf[ni], acc[mi][ni]);
    }
  }
  float ls = 0.f, lss = 0.f;
  #pragma unroll
  for (int mi = 0; mi < 4; ++mi) {
    #pragma unroll
    for (int ni = 0; ni < 4; ++ni) {
      int col = j0 + wc * 64 + ni * 16 + l15;
      float bv = bias[col];
      #pragma unroll
      for (int r = 0; r < 4; ++r) {
        int row = i0 + wr * 64 + mi * 16 + lhi * 4 + r;
        float val = acc[mi][ni][r] + bv;
        if (RES_) val += res[(size_t)row * Nc + col];
        if (GELU_) val = 0.5f * val * (1.f + erff(val * 0.70710678118654752f));
        if (BF16OUT) outb[(size_t)row * Nc + col] = f2bf(val);
        else out[(size_t)row * Nc + col] = val;
        if (STATS_) { ls += val; lss += val * val; }
      }
    }
  }
  if (STATS_) {
    #pragma unroll
    for (int off = 32; off > 0; off >>= 1) {
      ls += __shfl_down(ls, off); lss += __shfl_down(lss, off);
    }
    if (lane == 0) { red[wv * 2] = ls; red[wv * 2 + 1] = lss; }
    __syncthreads();
    if (t == 0) {
      int b = i0 >> 10;
      atomicAdd(&stats[b * 2],     red[0] + red[2] + red[4] + red[6]);
      atomicAdd(&stats[b * 2 + 1], red[1] + red[3] + red[5] + red[7]);
    }
  }
}

// ------------------------------- joint (N,D) LayerNorm apply (per-b scalars)
template<int BF16OUT>
__global__ __launch_bounds__(256) void k_ln(const float* __restrict__ y,
    const float* __restrict__ stats, const float* __restrict__ g,
    const float* __restrict__ bta, float* __restrict__ outp, u16* __restrict__ outb)
{
  size_t idx = (size_t)blockIdx.x * 256 + threadIdx.x;
  int i = (int)(idx / 768), col = (int)(idx % 768);
  int b = i >> 10, n = i & 1023;
  const float cnt = 786432.f;  // N*D
  float mu = stats[b * 2] / cnt;
  float var = stats[b * 2 + 1] / cnt - mu * mu;
  float r = rsqrtf(var + EPSV);
  size_t gi = (size_t)n * 768 + col;
  float v = (y[idx] - mu) * r * g[gi] + bta[gi];
  outp[idx] = v;
  if (BF16OUT) outb[idx] = f2bf(v);
}

extern "C" void kernel_launch(void* const* d_in, const int* in_sizes, int n_in,
                              void* d_out, int out_size, void* d_ws, size_t ws_size,
                              hipStream_t stream)
{
  const float* x   = (const float*)d_in[0];
  const float* qw  = (const float*)d_in[1];
  const float* kw  = (const float*)d_in[2];
  const float* vw  = (const float*)d_in[3];
  const float* rw  = (const float*)d_in[4];
  const float* bng = (const float*)d_in[6];
  const float* bnb = (const float*)d_in[7];
  const float* pw  = (const float*)d_in[8];
  const float* pb  = (const float*)d_in[9];
  const float* lng = (const float*)d_in[10];
  const float* lnb = (const float*)d_in[11];
  const float* fw1 = (const float*)d_in[12];
  const float* fb1 = (const float*)d_in[13];
  const float* fw2 = (const float*)d_in[14];
  const float* fb2 = (const float*)d_in[15];
  float* out = (float*)d_out;

  float* ws    = (float*)d_ws;
  float* stats = ws;                  // 64 ([0..15] BN, [16..23] LN1, [24..31] LN2)
  float* pstat = ws + 64;             // 131072 (1024 blocks x 8 waves x 16)
  float* vcs   = ws + 131136;         // 3072
  float* zp    = ws + 134208;         // 131072 (4 quarters x 32768)
  float* invZ  = ws + 265280;         // 32768
  float* vb    = ws + 298048;         // 3145728
  float* U0    = ws + 3443776;        // 3145728
  float* U1    = ws + 6589504;        // 3145728
  float* x1    = ws + 9735232;        // 3145728
  u16* u16b = (u16*)(ws + 12880960);
  u16* qhi  = u16b;
  u16* qlo  = u16b + 3145728;
  u16* khi  = u16b + 6291456;
  u16* klo  = u16b + 9437184;
  u16* vtr  = u16b + 12582912;
  u16* ubb  = u16b + 15728640;
  u16* pwb  = u16b + 18874368;
  u16* fw1b = u16b + 19464192;
  u16* fw2b = u16b + 21823488;        // ends 24182784 u16 (~100 MB total)
  float* U2 = vb;                     // vb dead after k_vtr/k_vcs
  float* U3 = x1;                     // x1 written only later by k_ln
  u16* x1b = qhi;                     // attention u16 dead after passB
  u16* hb  = qlo;                     // spans qlo..vtr
  float* y1 = U0;
  float* y2 = vb;

  hipMemsetAsync(stats, 0, 64 * sizeof(float), stream);
  k_f2b<<<1024, 256, 0, stream>>>(pw, pwb, 589824);
  k_f2b<<<2048, 256, 0, stream>>>(fw1, fw1b, 2359296);
  k_f2b<<<2048, 256, 0, stream>>>(fw2, fw2b, 2359296);

  k_conv<<<4096, 256, 0, stream>>>(x, qw, kw, vw, qhi, qlo, khi, klo, vb);
  k_passA<<<2048, 256, 0, stream>>>(qhi, qlo, khi, klo, zp);
  k_vtr<<<256, 256, 0, stream>>>(vb, vtr);
  k_vcs<<<32, 384, 0, stream>>>(vb, vcs);
  k_zmerge<<<128, 256, 0, stream>>>(zp, invZ);
  k_passB<<<1024, 512, 0, stream>>>(qhi, qlo, khi, klo, vtr, invZ, rw,
                                    U0, U1, U2, U3, pstat);
  k_statred<<<1, 256, 0, stream>>>(pstat, stats);
  k_bnfin<<<12288, 256, 0, stream>>>(U0, U1, U2, U3, vcs, stats, bng, bnb, ubb);

  k_gemm<0,1,1,0><<<dim3(6, 32), 256, 0, stream>>>(ubb, pwb, pb, x, y1, nullptr, 768, 768, stats + 16);
  k_ln<1><<<12288, 256, 0, stream>>>(y1, stats + 16, lng, lnb, x1, x1b);
  k_gemm<1,0,0,1><<<dim3(24, 32), 256, 0, stream>>>(x1b, fw1b, fb1, nullptr, nullptr, hb, 768, 3072, nullptr);
  k_gemm<0,1,1,0><<<dim3(6, 32), 256, 0, stream>>>(hb, fw2b, fb2, x1, y2, nullptr, 3072, 768, stats + 24);
  k_ln<0><<<12288, 256, 0, stream>>>(y2, stats + 24, lng, lnb, out, nullptr);
}

// Round 5
// 373.393 us; speedup vs baseline: 1.1410x; 1.1410x over previous
//
#include <hip/hip_runtime.h>
#include <math.h>

// ViT encoder block (DeepViT ReAttention), B=4 N=1024 D=768 H=8 hd=96 Hdim=3072
// R5: passB de-spill (streamed K/Q frags per kk, unroll-1 head loop, VGPR<=128
// via launch_bounds(512,4)); parallel 2-stage BN stat reduction.

typedef unsigned short u16;
typedef unsigned int u32;
typedef __bf16 bf16x8 __attribute__((ext_vector_type(8)));
typedef float f32x4 __attribute__((ext_vector_type(4)));

#define EPSV 1e-5f
#define SL2E 0.14724444620253177f   // 96^-0.5 * log2(e), folded into q at conv
#define EXPC -11.541560327111707f   // -8 * log2(e)

__device__ __forceinline__ u16 f2bf(float f) {
  union { float f; u32 u; } v; v.f = f;
  u32 u = v.u + 0x7fffu + ((v.u >> 16) & 1u);
  return (u16)(u >> 16);
}
__device__ __forceinline__ float bf2f(u16 h) {
  union { u32 u; float f; } v; v.u = ((u32)h) << 16; return v.f;
}
__device__ __forceinline__ f32x4 mfma16(bf16x8 a, bf16x8 b, f32x4 c) {
  return __builtin_amdgcn_mfma_f32_16x16x32_bf16(a, b, c, 0, 0, 0);
}
__device__ __forceinline__ void gload16(const void* gp, void* lp) {
  __builtin_amdgcn_global_load_lds(
      (const __attribute__((address_space(1))) u32*)gp,
      (__attribute__((address_space(3))) u32*)lp, 16, 0, 0);
}

// ---------------------------------------------------------------- fp32 -> bf16
__global__ __launch_bounds__(256) void k_f2b(const float* __restrict__ s,
                                             u16* __restrict__ d, int n) {
  int i = blockIdx.x * 256 + threadIdx.x;
  int stride = gridDim.x * 256;
  for (; i < n; i += stride) d[i] = f2bf(s[i]);
}

// ---------------------------------------------------------------- conv 3x3 QKV
__global__ __launch_bounds__(256) void k_conv(const float* __restrict__ x,
    const float* __restrict__ wq, const float* __restrict__ wk, const float* __restrict__ wv,
    u16* __restrict__ qhi, u16* __restrict__ qlo,
    u16* __restrict__ khi, u16* __restrict__ klo,
    float* __restrict__ vb)
{
  __shared__ float patch[768], swq[81], swk[81], swv[81];
  int bid = blockIdx.x;            // b*1024 + n
  int b = bid >> 10, n = bid & 1023;
  int t = threadIdx.x;
  const float* xr = x + (size_t)bid * 768;
  patch[t] = xr[t]; patch[t + 256] = xr[t + 256]; patch[t + 512] = xr[t + 512];
  if (t < 81) { swq[t] = wq[t]; swk[t] = wk[t]; swv[t] = wv[t]; }
  __syncthreads();
  #pragma unroll
  for (int r = 0; r < 3; ++r) {
    int f = t + 256 * r;                       // c*256 + p*16 + q
    int o = f >> 8, rem = f & 255, pp = rem >> 4, qq = rem & 15;
    float aq = 0.f, ak = 0.f, av = 0.f;
    #pragma unroll
    for (int i = 0; i < 3; ++i)
      #pragma unroll
      for (int dp = 0; dp < 3; ++dp) {
        int ip = pp + dp - 1;
        if (ip < 0 || ip > 15) continue;
        #pragma unroll
        for (int dq = 0; dq < 3; ++dq) {
          int iq = qq + dq - 1;
          if (iq < 0 || iq > 15) continue;
          float pv = patch[i * 256 + ip * 16 + iq];
          int wi = ((o * 3 + i) * 3 + dp) * 3 + dq;
          aq += swq[wi] * pv; ak += swk[wi] * pv; av += swv[wi] * pv;
        }
      }
    int h = f / 96, d = f - h * 96;
    size_t oi = ((size_t)(b * 8 + h) * 1024 + n) * 96 + d;
    float aqs = aq * SL2E;           // fold softmax scale + log2e into q
    u16 qh_ = f2bf(aqs); qhi[oi] = qh_; qlo[oi] = f2bf(aqs - bf2f(qh_));
    u16 kh_ = f2bf(ak);  khi[oi] = kh_; klo[oi] = f2bf(ak - bf2f(kh_));
    vb[oi] = av;
  }
}

// ------------------------------- V transpose: [bh][n][d] f32 -> [bh][d][n] bf16
__global__ __launch_bounds__(256) void k_vtr(const float* __restrict__ vb,
                                             u16* __restrict__ vtr)
{
  __shared__ u16 lds[12288];     // [96 d][128 n]
  int bid = blockIdx.x;          // bh*8 + ntile
  int bh = bid >> 3, n0 = (bid & 7) * 128;
  int t = threadIdx.x;
  int n = t >> 1, dh = (t & 1) * 48;
  const float* src = vb + ((size_t)bh * 1024 + n0 + n) * 96 + dh;
  #pragma unroll
  for (int j4 = 0; j4 < 12; ++j4) {
    float4 v = *(const float4*)(src + j4 * 4);
    int d = dh + j4 * 4;
    lds[(d + 0) * 128 + n] = f2bf(v.x);
    lds[(d + 1) * 128 + n] = f2bf(v.y);
    lds[(d + 2) * 128 + n] = f2bf(v.z);
    lds[(d + 3) * 128 + n] = f2bf(v.w);
  }
  __syncthreads();
  #pragma unroll
  for (int j = 0; j < 48; ++j) {
    int flat = t + 256 * j;
    int d = flat >> 7, n2 = flat & 127;
    vtr[((size_t)bh * 96 + d) * 1024 + n0 + n2] = lds[flat];
  }
}

// ---------------- pass A: z[n] partial = sum_m exp2(C + EXPC) over an m-quarter
#define LOADK(KH, KL, M)                                            \
  {                                                                 \
    size_t ko_ = (kbase + (M) + l15) * 96 + (size_t)(lhi * 8);      \
    _Pragma("unroll")                                               \
    for (int kk = 0; kk < 3; ++kk) {                                \
      KH[kk] = *(const bf16x8*)(khi + ko_ + kk * 32);               \
      KL[kk] = *(const bf16x8*)(klo + ko_ + kk * 32);               \
    }                                                               \
  }

__global__ __launch_bounds__(256, 4) void k_passA(
    const u16* __restrict__ qhi, const u16* __restrict__ qlo,
    const u16* __restrict__ khi, const u16* __restrict__ klo,
    float* __restrict__ zp)
{
  int bid = blockIdx.x;          // bh*64 + tile*4 + qtr
  int bh = bid >> 6, rest = bid & 63, tile = rest >> 2, qtr = rest & 3;
  int t = threadIdx.x, lane = t & 63, wv = t >> 6;
  int l15 = lane & 15, lhi = lane >> 4;
  int n0 = tile * 64 + wv * 16;
  size_t qoff = ((size_t)bh * 1024 + n0 + l15) * 96 + lhi * 8;
  bf16x8 qh[3], ql[3];
  #pragma unroll
  for (int kk = 0; kk < 3; ++kk) {
    qh[kk] = *(const bf16x8*)(qhi + qoff + kk * 32);
    ql[kk] = *(const bf16x8*)(qlo + qoff + kk * 32);
  }
  size_t kbase = (size_t)bh * 1024;
  float z[4] = {0.f, 0.f, 0.f, 0.f};
  bf16x8 khA[3], klA[3], khB[3], klB[3];
  int m0 = qtr * 256;
  LOADK(khA, klA, m0)
  for (int it = 0; it < 8; ++it) {
    int mb = m0 + it * 32;
    LOADK(khB, klB, mb + 16)
    {
      f32x4 C = {0.f, 0.f, 0.f, 0.f};
      #pragma unroll
      for (int kk = 0; kk < 3; ++kk) {
        C = mfma16(qh[kk], khA[kk], C);
        C = mfma16(qh[kk], klA[kk], C);
        C = mfma16(ql[kk], khA[kk], C);
      }
      #pragma unroll
      for (int r = 0; r < 4; ++r) z[r] += exp2f(C[r] + EXPC);
    }
    if (it < 7) LOADK(khA, klA, mb + 32)
    {
      f32x4 C = {0.f, 0.f, 0.f, 0.f};
      #pragma unroll
      for (int kk = 0; kk < 3; ++kk) {
        C = mfma16(qh[kk], khB[kk], C);
        C = mfma16(qh[kk], klB[kk], C);
        C = mfma16(ql[kk], khB[kk], C);
      }
      #pragma unroll
      for (int r = 0; r < 4; ++r) z[r] += exp2f(C[r] + EXPC);
    }
  }
  #pragma unroll
  for (int off = 1; off < 16; off <<= 1)
    #pragma unroll
    for (int r = 0; r < 4; ++r) z[r] += __shfl_xor(z[r], off);
  if (l15 == 0) {
    #pragma unroll
    for (int r = 0; r < 4; ++r)
      zp[qtr * 32768 + bh * 1024 + n0 + lhi * 4 + r] = z[r];
  }
}

// --------------------------------------- merge 4 z-quarters -> invZ
__global__ __launch_bounds__(256) void k_zmerge(const float* __restrict__ zp,
                                                float* __restrict__ invZ)
{
  int idx = blockIdx.x * 256 + threadIdx.x;   // < 32768
  float z = zp[idx] + zp[32768 + idx] + zp[65536 + idx] + zp[98304 + idx];
  invZ[idx] = 1.f / z;
}

// ---------------- pass B: per block (b, ntile, mq): phase1 = waves own 32-m
// chunks, compute all-head scores (swapped QK^T, permuted K rows), lane-local
// softmax+mix -> bf16 PV A-frags to LDS; barrier; phase2 = waves own heads,
// PV over the 256-m quarter. Streamed frag loads keep live regs ~110 (<128).
__global__ __launch_bounds__(512, 4) void k_passB(
    const u16* __restrict__ qhi, const u16* __restrict__ qlo,
    const u16* __restrict__ khi, const u16* __restrict__ klo,
    const u16* __restrict__ vtr, const float* __restrict__ invZ,
    const float* __restrict__ rw,
    float* __restrict__ U0, float* __restrict__ U1,
    float* __restrict__ U2, float* __restrict__ U3,
    float* __restrict__ pstat)
{
  __shared__ u16 clds[32768];    // 64KB: [w*8+g][lane] 16B frags
  int bid = blockIdx.x;          // b*256 + nt*4 + mq
  int b = bid >> 8, rest = bid & 255, nt = rest >> 2, mq = rest & 3;
  int n0 = nt * 16;
  int t = threadIdx.x, lane = t & 63, w = t >> 6;
  int l15 = lane & 15, lhi = lane >> 4;
  int mbase = mq * 256 + w * 32;                       // phase-1 m chunk
  int mrow0 = mbase + ((l15 >> 2) * 8) + (l15 & 3);    // permuted K row, tile0

  // per-g mix accumulators, init with analytic centering -sum(W_g)/1024
  float cm[8][8];
  #pragma unroll
  for (int g = 0; g < 8; ++g) {
    float wsum = 0.f;
    #pragma unroll
    for (int h = 0; h < 8; ++h) wsum += rw[g * 8 + h];
    float cg = -wsum * (1.f / 1024.f);
    #pragma unroll
    for (int jj = 0; jj < 8; ++jj) cm[g][jj] = cg;
  }

  #pragma unroll 1
  for (int h = 0; h < 8; ++h) {
    size_t base = (size_t)(b * 8 + h) * 1024;
    const u16* qhp = qhi + (base + n0 + l15) * 96 + lhi * 8;
    const u16* qlp = qlo + (base + n0 + l15) * 96 + lhi * 8;
    const u16* khp = khi + (base + mrow0) * 96 + lhi * 8;
    const u16* klp = klo + (base + mrow0) * 96 + lhi * 8;
    f32x4 C0 = {0.f, 0.f, 0.f, 0.f}, C1 = {0.f, 0.f, 0.f, 0.f};
    #pragma unroll
    for (int kk = 0; kk < 3; ++kk) {
      bf16x8 qh8 = *(const bf16x8*)(qhp + kk * 32);
      bf16x8 ql8 = *(const bf16x8*)(qlp + kk * 32);
      bf16x8 kh0 = *(const bf16x8*)(khp + kk * 32);
      bf16x8 kl0 = *(const bf16x8*)(klp + kk * 32);
      bf16x8 kh1 = *(const bf16x8*)(khp + 384 + kk * 32);  // +4 rows
      bf16x8 kl1 = *(const bf16x8*)(klp + 384 + kk * 32);
      C0 = mfma16(kh0, qh8, C0);   // q_hi*k_hi
      C0 = mfma16(kl0, qh8, C0);   // q_hi*k_lo
      C0 = mfma16(kh0, ql8, C0);   // q_lo*k_hi
      C1 = mfma16(kh1, qh8, C1);
      C1 = mfma16(kl1, qh8, C1);
      C1 = mfma16(kh1, ql8, C1);
    }
    float iz = invZ[base + n0 + l15];
    #pragma unroll
    for (int r = 0; r < 4; ++r) {
      float p0 = exp2f(C0[r] + EXPC) * iz;   // m-off = lhi*8 + r
      float p1 = exp2f(C1[r] + EXPC) * iz;   // m-off = lhi*8 + 4 + r
      #pragma unroll
      for (int g = 0; g < 8; ++g) {
        float wgh = rw[g * 8 + h];
        cm[g][r]     += wgh * p0;
        cm[g][4 + r] += wgh * p1;
      }
    }
  }

  // BN stats (per g, this wave's (16n x 32m) patch)
  {
    float sc[8], scc[8];
    #pragma unroll
    for (int g = 0; g < 8; ++g) {
      float s = 0.f, ss = 0.f;
      #pragma unroll
      for (int jj = 0; jj < 8; ++jj) { float v = cm[g][jj]; s += v; ss += v * v; }
      sc[g] = s; scc[g] = ss;
    }
    #pragma unroll
    for (int off = 32; off > 0; off >>= 1)
      #pragma unroll
      for (int g = 0; g < 8; ++g) {
        sc[g] += __shfl_down(sc[g], off);
        scc[g] += __shfl_down(scc[g], off);
      }
    if (lane == 0) {
      #pragma unroll
      for (int g = 0; g < 8; ++g) {
        pstat[(size_t)(bid * 8 + w) * 16 + g] = sc[g];
        pstat[(size_t)(bid * 8 + w) * 16 + 8 + g] = scc[g];
      }
    }
  }

  // pack + stash PV A-frags
  #pragma unroll
  for (int g = 0; g < 8; ++g) {
    union { u16 us[8]; bf16x8 bv; } pk;
    #pragma unroll
    for (int jj = 0; jj < 8; ++jj) pk.us[jj] = f2bf(cm[g][jj]);
    *(bf16x8*)&clds[((w * 8 + g) * 64 + lane) * 8] = pk.bv;
  }
  __syncthreads();

  // phase 2: wave w = head w, PV over all 8 m-chunks of this quarter
  f32x4 acc[6];
  #pragma unroll
  for (int ds = 0; ds < 6; ++ds) acc[ds] = (f32x4){0.f, 0.f, 0.f, 0.f};
  size_t vbase = (size_t)(b * 8 + w) * 96;
  for (int mc = 0; mc < 8; ++mc) {
    bf16x8 af = *(const bf16x8*)&clds[((mc * 8 + w) * 64 + lane) * 8];
    int mof = mq * 256 + mc * 32 + lhi * 8;
    #pragma unroll
    for (int ds = 0; ds < 6; ++ds) {
      bf16x8 vf = *(const bf16x8*)(vtr + (vbase + ds * 16 + l15) * 1024 + mof);
      acc[ds] = mfma16(af, vf, acc[ds]);
    }
  }
  float* Uq = (mq == 0) ? U0 : (mq == 1) ? U1 : (mq == 2) ? U2 : U3;
  #pragma unroll
  for (int ds = 0; ds < 6; ++ds)
    #pragma unroll
    for (int r = 0; r < 4; ++r) {
      int n = lhi * 4 + r;
      Uq[((size_t)(b * 1024 + n0 + n)) * 768 + w * 96 + ds * 16 + l15] = acc[ds][r];
    }
}

// ------------------------------------------------- colsum(V) per (b,h,d), fp32
__global__ __launch_bounds__(384) void k_vcs(const float* __restrict__ vb,
                                             float* __restrict__ vcs)
{
  __shared__ float part[4][96];
  int bh = blockIdx.x, t = threadIdx.x;
  int c = t % 96, g4 = t / 96;
  float a = 0.f;
  const float* vp = vb + (size_t)bh * 98304 + (size_t)g4 * 24576 + c;
  for (int m = 0; m < 256; ++m) a += vp[m * 96];
  part[g4][c] = a;
  __syncthreads();
  if (t < 96) vcs[bh * 96 + t] = part[0][t] + part[1][t] + part[2][t] + part[3][t];
}

// --------------------- BN partial reduce stage 1: 64 blocks x 128 rows -> [64][16]
__global__ __launch_bounds__(256) void k_statred1(const float* __restrict__ pstat,
                                                  float* __restrict__ pred)
{
  __shared__ float part[16][17];
  int bb = blockIdx.x, t = threadIdx.x;
  int j = t >> 4, s = t & 15;
  float a = 0.f;
  #pragma unroll
  for (int k2 = 0; k2 < 8; ++k2)
    a += pstat[(size_t)(bb * 128 + s + 16 * k2) * 16 + j];
  part[j][s] = a;
  __syncthreads();
  if (t < 16) {
    float v = 0.f;
    #pragma unroll
    for (int s2 = 0; s2 < 16; ++s2) v += part[t][s2];
    pred[bb * 16 + t] = v;
  }
}

// --------------------- BN partial reduce stage 2: [64][16] -> stats[16]
__global__ __launch_bounds__(256) void k_statred2(const float* __restrict__ pred,
                                                  float* __restrict__ stats)
{
  __shared__ float part[16][17];
  int t = threadIdx.x;
  int j = t >> 4, s = t & 15;
  float a = 0.f;
  #pragma unroll
  for (int k2 = 0; k2 < 4; ++k2)
    a += pred[(size_t)(s + 16 * k2) * 16 + j];
  part[j][s] = a;
  __syncthreads();
  if (t < 16) {
    float v = 0.f;
    #pragma unroll
    for (int s2 = 0; s2 < 16; ++s2) v += part[t][s2];
    stats[t] = v;
  }
}

// ------------- BN affine: ubb = bf16(sg*(U0+U1+U2+U3) + (bnb - sg*mc)*colsum(V))
__global__ __launch_bounds__(256) void k_bnfin(const float* __restrict__ U0,
    const float* __restrict__ U1, const float* __restrict__ U2,
    const float* __restrict__ U3, const float* __restrict__ vcs,
    const float* __restrict__ stats, const float* __restrict__ bng,
    const float* __restrict__ bnb, u16* __restrict__ ubb)
{
  size_t idx = (size_t)blockIdx.x * 256 + threadIdx.x;
  int col = (int)(idx % 768); int i = (int)(idx / 768); int b = i >> 10;
  int g = col / 96, d = col - g * 96;
  const float cnt = 4194304.f;  // B*N*N
  float mc = stats[g] / cnt;
  float var = stats[8 + g] / cnt - mc * mc;
  float sg = bng[g] * rsqrtf(var + EPSV);
  float tg = bnb[g] - sg * mc;
  float u = (U0[idx] + U1[idx]) + (U2[idx] + U3[idx]);
  ubb[idx] = f2bf(sg * u + tg * vcs[(b * 8 + g) * 96 + d]);
}

// -------- bf16 MFMA GEMM: out = A[M,K]@W[N,K]^T + bias (+res)(+gelu)(+LN stats)
template<int GELU_, int RES_, int STATS_, int BF16OUT>
__global__ __launch_bounds__(256) void k_gemm(
    const u16* __restrict__ A, const u16* __restrict__ W,
    const float* __restrict__ bias, const float* __restrict__ res,
    float* __restrict__ out, u16* __restrict__ outb,
    int K, int Nc, float* __restrict__ stats)
{
  __shared__ u16 As[8192], Bs[8192];   // 128 rows x 64 cols, XOR-swizzled
  __shared__ float red[8];
  int t = threadIdx.x, lane = t & 63, wv = t >> 6;
  int l15 = lane & 15, lhi = lane >> 4;
  int i0 = blockIdx.y * 128, j0 = blockIdx.x * 128;
  int wr = wv >> 1, wc = wv & 1;
  f32x4 acc[4][4];
  #pragma unroll
  for (int mi = 0; mi < 4; ++mi)
    #pragma unroll
    for (int ni = 0; ni < 4; ++ni) acc[mi][ni] = (f32x4){0.f, 0.f, 0.f, 0.f};
  int rA = lane >> 3;
  int colel = 8 * ((lane & 7) ^ rA);   // pre-swizzled global source column
  for (int k0 = 0; k0 < K; k0 += 64) {
    if (k0) __syncthreads();
    #pragma unroll
    for (int i = 0; i < 4; ++i) {
      int cA = wv * 4 + i;
      int r = cA * 8 + rA;
      gload16(A + (size_t)(i0 + r) * K + k0 + colel, &As[cA * 512]);
      gload16(W + (size_t)(j0 + r) * K + k0 + colel, &Bs[cA * 512]);
    }
    __syncthreads();
    #pragma unroll
    for (int ks = 0; ks < 2; ++ks) {
      bf16x8 af[4], bf[4];
      #pragma unroll
      for (int mi = 0; mi < 4; ++mi) {
        int r2 = wr * 64 + mi * 16 + l15;
        af[mi] = *(const bf16x8*)&As[r2 * 64 + ((ks * 32 + lhi * 8) ^ (8 * (r2 & 7)))];
      }
      #pragma unroll
      for (int ni = 0; ni < 4; ++ni) {
        int r3 = wc * 64 + ni * 16 + l15;
        bf[ni] = *(const bf16x8*)&Bs[r3 * 64 + ((ks * 32 + lhi * 8) ^ (8 * (r3 & 7)))];
      }
      #pragma unroll
      for (int mi = 0; mi < 4; ++mi)
        #pragma unroll
        for (int ni = 0; ni < 4; ++ni)
          acc[mi][ni] = mfma16(af[mi], bf[ni], acc[mi][ni]);
    }
  }
  float ls = 0.f, lss = 0.f;
  #pragma unroll
  for (int mi = 0; mi < 4; ++mi) {
    #pragma unroll
    for (int ni = 0; ni < 4; ++ni) {
      int col = j0 + wc * 64 + ni * 16 + l15;
      float bv = bias[col];
      #pragma unroll
      for (int r = 0; r < 4; ++r) {
        int row = i0 + wr * 64 + mi * 16 + lhi * 4 + r;
        float val = acc[mi][ni][r] + bv;
        if (RES_) val += res[(size_t)row * Nc + col];
        if (GELU_) val = 0.5f * val * (1.f + erff(val * 0.70710678118654752f));
        if (BF16OUT) outb[(size_t)row * Nc + col] = f2bf(val);
        else out[(size_t)row * Nc + col] = val;
        if (STATS_) { ls += val; lss += val * val; }
      }
    }
  }
  if (STATS_) {
    #pragma unroll
    for (int off = 32; off > 0; off >>= 1) {
      ls += __shfl_down(ls, off); lss += __shfl_down(lss, off);
    }
    if (lane == 0) { red[wv * 2] = ls; red[wv * 2 + 1] = lss; }
    __syncthreads();
    if (t == 0) {
      int b = i0 >> 10;
      atomicAdd(&stats[b * 2],     red[0] + red[2] + red[4] + red[6]);
      atomicAdd(&stats[b * 2 + 1], red[1] + red[3] + red[5] + red[7]);
    }
  }
}

// ------------------------------- joint (N,D) LayerNorm apply (per-b scalars)
template<int BF16OUT>
__global__ __launch_bounds__(256) void k_ln(const float* __restrict__ y,
    const float* __restrict__ stats, const float* __restrict__ g,
    const float* __restrict__ bta, float* __restrict__ outp, u16* __restrict__ outb)
{
  size_t idx = (size_t)blockIdx.x * 256 + threadIdx.x;
  int i = (int)(idx / 768), col = (int)(idx % 768);
  int b = i >> 10, n = i & 1023;
  const float cnt = 786432.f;  // N*D
  float mu = stats[b * 2] / cnt;
  float var = stats[b * 2 + 1] / cnt - mu * mu;
  float r = rsqrtf(var + EPSV);
  size_t gi = (size_t)n * 768 + col;
  float v = (y[idx] - mu) * r * g[gi] + bta[gi];
  outp[idx] = v;
  if (BF16OUT) outb[idx] = f2bf(v);
}

extern "C" void kernel_launch(void* const* d_in, const int* in_sizes, int n_in,
                              void* d_out, int out_size, void* d_ws, size_t ws_size,
                              hipStream_t stream)
{
  const float* x   = (const float*)d_in[0];
  const float* qw  = (const float*)d_in[1];
  const float* kw  = (const float*)d_in[2];
  const float* vw  = (const float*)d_in[3];
  const float* rw  = (const float*)d_in[4];
  const float* bng = (const float*)d_in[6];
  const float* bnb = (const float*)d_in[7];
  const float* pw  = (const float*)d_in[8];
  const float* pb  = (const float*)d_in[9];
  const float* lng = (const float*)d_in[10];
  const float* lnb = (const float*)d_in[11];
  const float* fw1 = (const float*)d_in[12];
  const float* fb1 = (const float*)d_in[13];
  const float* fw2 = (const float*)d_in[14];
  const float* fb2 = (const float*)d_in[15];
  float* out = (float*)d_out;

  float* ws    = (float*)d_ws;
  float* stats = ws;                  // 64 ([0..15] BN, [16..23] LN1, [24..31] LN2)
  float* pstat = ws + 64;             // 131072 (1024 blocks x 8 waves x 16)
  float* vcs   = ws + 131136;         // 3072
  float* zp    = ws + 134208;         // 131072 (4 quarters x 32768)
  float* invZ  = ws + 265280;         // 32768
  float* vb    = ws + 298048;         // 3145728
  float* U0    = ws + 3443776;        // 3145728
  float* U1    = ws + 6589504;        // 3145728
  float* x1    = ws + 9735232;        // 3145728
  u16* u16b = (u16*)(ws + 12880960);
  u16* qhi  = u16b;
  u16* qlo  = u16b + 3145728;
  u16* khi  = u16b + 6291456;
  u16* klo  = u16b + 9437184;
  u16* vtr  = u16b + 12582912;
  u16* ubb  = u16b + 15728640;
  u16* pwb  = u16b + 18874368;
  u16* fw1b = u16b + 19464192;
  u16* fw2b = u16b + 21823488;        // ends 24182784 u16 (~100 MB total)
  float* U2 = vb;                     // vb dead after k_vtr/k_vcs
  float* U3 = x1;                     // x1 written only later by k_ln
  float* pred = zp;                   // zp dead after k_zmerge (1024 floats)
  u16* x1b = qhi;                     // attention u16 dead after passB
  u16* hb  = qlo;                     // spans qlo..vtr
  float* y1 = U0;
  float* y2 = vb;

  hipMemsetAsync(stats, 0, 64 * sizeof(float), stream);
  k_f2b<<<1024, 256, 0, stream>>>(pw, pwb, 589824);
  k_f2b<<<2048, 256, 0, stream>>>(fw1, fw1b, 2359296);
  k_f2b<<<2048, 256, 0, stream>>>(fw2, fw2b, 2359296);

  k_conv<<<4096, 256, 0, stream>>>(x, qw, kw, vw, qhi, qlo, khi, klo, vb);
  k_passA<<<2048, 256, 0, stream>>>(qhi, qlo, khi, klo, zp);
  k_vtr<<<256, 256, 0, stream>>>(vb, vtr);
  k_vcs<<<32, 384, 0, stream>>>(vb, vcs);
  k_zmerge<<<128, 256, 0, stream>>>(zp, invZ);
  k_passB<<<1024, 512, 0, stream>>>(qhi, qlo, khi, klo, vtr, invZ, rw,
                                    U0, U1, U2, U3, pstat);
  k_statred1<<<64, 256, 0, stream>>>(pstat, pred);
  k_statred2<<<1, 256, 0, stream>>>(pred, stats);
  k_bnfin<<<12288, 256, 0, stream>>>(U0, U1, U2, U3, vcs, stats, bng, bnb, ubb);

  k_gemm<0,1,1,0><<<dim3(6, 32), 256, 0, stream>>>(ubb, pwb, pb, x, y1, nullptr, 768, 768, stats + 16);
  k_ln<1><<<12288, 256, 0, stream>>>(y1, stats + 16, lng, lnb, x1, x1b);
  k_gemm<1,0,0,1><<<dim3(24, 32), 256, 0, stream>>>(x1b, fw1b, fb1, nullptr, nullptr, hb, 768, 3072, nullptr);
  k_gemm<0,1,1,0><<<dim3(6, 32), 256, 0, stream>>>(hb, fw2b, fb2, x1, y2, nullptr, 3072, 768, stats + 24);
  k_ln<0><<<12288, 256, 0, stream>>>(y2, stats + 24, lng, lnb, out, nullptr);
}

// Round 6
// 372.247 us; speedup vs baseline: 1.1445x; 1.0031x over previous
//
#include <hip/hip_runtime.h>
#include <math.h>

// ViT encoder block (DeepViT ReAttention), B=4 N=1024 D=768 H=8 hd=96 Hdim=3072
// R6: passB spill-free restructure — phase1 writes per-head bf16 P frags to LDS
// (no mix registers), phase2 mixes per-head frags with cm8[8] (wave = head g).

typedef unsigned short u16;
typedef unsigned int u32;
typedef __bf16 bf16x8 __attribute__((ext_vector_type(8)));
typedef float f32x4 __attribute__((ext_vector_type(4)));

#define EPSV 1e-5f
#define SL2E 0.14724444620253177f   // 96^-0.5 * log2(e), folded into q at conv
#define EXPC -11.541560327111707f   // -8 * log2(e)

__device__ __forceinline__ u16 f2bf(float f) {
  union { float f; u32 u; } v; v.f = f;
  u32 u = v.u + 0x7fffu + ((v.u >> 16) & 1u);
  return (u16)(u >> 16);
}
__device__ __forceinline__ float bf2f(u16 h) {
  union { u32 u; float f; } v; v.u = ((u32)h) << 16; return v.f;
}
__device__ __forceinline__ f32x4 mfma16(bf16x8 a, bf16x8 b, f32x4 c) {
  return __builtin_amdgcn_mfma_f32_16x16x32_bf16(a, b, c, 0, 0, 0);
}
__device__ __forceinline__ void gload16(const void* gp, void* lp) {
  __builtin_amdgcn_global_load_lds(
      (const __attribute__((address_space(1))) u32*)gp,
      (__attribute__((address_space(3))) u32*)lp, 16, 0, 0);
}

// ---------------------------------------------------------------- fp32 -> bf16
__global__ __launch_bounds__(256) void k_f2b(const float* __restrict__ s,
                                             u16* __restrict__ d, int n) {
  int i = blockIdx.x * 256 + threadIdx.x;
  int stride = gridDim.x * 256;
  for (; i < n; i += stride) d[i] = f2bf(s[i]);
}

// ---------------------------------------------------------------- conv 3x3 QKV
__global__ __launch_bounds__(256) void k_conv(const float* __restrict__ x,
    const float* __restrict__ wq, const float* __restrict__ wk, const float* __restrict__ wv,
    u16* __restrict__ qhi, u16* __restrict__ qlo,
    u16* __restrict__ khi, u16* __restrict__ klo,
    float* __restrict__ vb)
{
  __shared__ float patch[768], swq[81], swk[81], swv[81];
  int bid = blockIdx.x;            // b*1024 + n
  int b = bid >> 10, n = bid & 1023;
  int t = threadIdx.x;
  const float* xr = x + (size_t)bid * 768;
  patch[t] = xr[t]; patch[t + 256] = xr[t + 256]; patch[t + 512] = xr[t + 512];
  if (t < 81) { swq[t] = wq[t]; swk[t] = wk[t]; swv[t] = wv[t]; }
  __syncthreads();
  #pragma unroll
  for (int r = 0; r < 3; ++r) {
    int f = t + 256 * r;                       // c*256 + p*16 + q
    int o = f >> 8, rem = f & 255, pp = rem >> 4, qq = rem & 15;
    float aq = 0.f, ak = 0.f, av = 0.f;
    #pragma unroll
    for (int i = 0; i < 3; ++i)
      #pragma unroll
      for (int dp = 0; dp < 3; ++dp) {
        int ip = pp + dp - 1;
        if (ip < 0 || ip > 15) continue;
        #pragma unroll
        for (int dq = 0; dq < 3; ++dq) {
          int iq = qq + dq - 1;
          if (iq < 0 || iq > 15) continue;
          float pv = patch[i * 256 + ip * 16 + iq];
          int wi = ((o * 3 + i) * 3 + dp) * 3 + dq;
          aq += swq[wi] * pv; ak += swk[wi] * pv; av += swv[wi] * pv;
        }
      }
    int h = f / 96, d = f - h * 96;
    size_t oi = ((size_t)(b * 8 + h) * 1024 + n) * 96 + d;
    float aqs = aq * SL2E;           // fold softmax scale + log2e into q
    u16 qh_ = f2bf(aqs); qhi[oi] = qh_; qlo[oi] = f2bf(aqs - bf2f(qh_));
    u16 kh_ = f2bf(ak);  khi[oi] = kh_; klo[oi] = f2bf(ak - bf2f(kh_));
    vb[oi] = av;
  }
}

// ------------------------------- V transpose: [bh][n][d] f32 -> [bh][d][n] bf16
__global__ __launch_bounds__(256) void k_vtr(const float* __restrict__ vb,
                                             u16* __restrict__ vtr)
{
  __shared__ u16 lds[12288];     // [96 d][128 n]
  int bid = blockIdx.x;          // bh*8 + ntile
  int bh = bid >> 3, n0 = (bid & 7) * 128;
  int t = threadIdx.x;
  int n = t >> 1, dh = (t & 1) * 48;
  const float* src = vb + ((size_t)bh * 1024 + n0 + n) * 96 + dh;
  #pragma unroll
  for (int j4 = 0; j4 < 12; ++j4) {
    float4 v = *(const float4*)(src + j4 * 4);
    int d = dh + j4 * 4;
    lds[(d + 0) * 128 + n] = f2bf(v.x);
    lds[(d + 1) * 128 + n] = f2bf(v.y);
    lds[(d + 2) * 128 + n] = f2bf(v.z);
    lds[(d + 3) * 128 + n] = f2bf(v.w);
  }
  __syncthreads();
  #pragma unroll
  for (int j = 0; j < 48; ++j) {
    int flat = t + 256 * j;
    int d = flat >> 7, n2 = flat & 127;
    vtr[((size_t)bh * 96 + d) * 1024 + n0 + n2] = lds[flat];
  }
}

// ---------------- pass A: z[n] partial = sum_m exp2(C + EXPC) over an m-quarter
#define LOADK(KH, KL, M)                                            \
  {                                                                 \
    size_t ko_ = (kbase + (M) + l15) * 96 + (size_t)(lhi * 8);      \
    _Pragma("unroll")                                               \
    for (int kk = 0; kk < 3; ++kk) {                                \
      KH[kk] = *(const bf16x8*)(khi + ko_ + kk * 32);               \
      KL[kk] = *(const bf16x8*)(klo + ko_ + kk * 32);               \
    }                                                               \
  }

__global__ __launch_bounds__(256, 4) void k_passA(
    const u16* __restrict__ qhi, const u16* __restrict__ qlo,
    const u16* __restrict__ khi, const u16* __restrict__ klo,
    float* __restrict__ zp)
{
  int bid = blockIdx.x;          // bh*64 + tile*4 + qtr
  int bh = bid >> 6, rest = bid & 63, tile = rest >> 2, qtr = rest & 3;
  int t = threadIdx.x, lane = t & 63, wv = t >> 6;
  int l15 = lane & 15, lhi = lane >> 4;
  int n0 = tile * 64 + wv * 16;
  size_t qoff = ((size_t)bh * 1024 + n0 + l15) * 96 + lhi * 8;
  bf16x8 qh[3], ql[3];
  #pragma unroll
  for (int kk = 0; kk < 3; ++kk) {
    qh[kk] = *(const bf16x8*)(qhi + qoff + kk * 32);
    ql[kk] = *(const bf16x8*)(qlo + qoff + kk * 32);
  }
  size_t kbase = (size_t)bh * 1024;
  float z[4] = {0.f, 0.f, 0.f, 0.f};
  bf16x8 khA[3], klA[3], khB[3], klB[3];
  int m0 = qtr * 256;
  LOADK(khA, klA, m0)
  for (int it = 0; it < 8; ++it) {
    int mb = m0 + it * 32;
    LOADK(khB, klB, mb + 16)
    {
      f32x4 C = {0.f, 0.f, 0.f, 0.f};
      #pragma unroll
      for (int kk = 0; kk < 3; ++kk) {
        C = mfma16(qh[kk], khA[kk], C);
        C = mfma16(qh[kk], klA[kk], C);
        C = mfma16(ql[kk], khA[kk], C);
      }
      #pragma unroll
      for (int r = 0; r < 4; ++r) z[r] += exp2f(C[r] + EXPC);
    }
    if (it < 7) LOADK(khA, klA, mb + 32)
    {
      f32x4 C = {0.f, 0.f, 0.f, 0.f};
      #pragma unroll
      for (int kk = 0; kk < 3; ++kk) {
        C = mfma16(qh[kk], khB[kk], C);
        C = mfma16(qh[kk], klB[kk], C);
        C = mfma16(ql[kk], khB[kk], C);
      }
      #pragma unroll
      for (int r = 0; r < 4; ++r) z[r] += exp2f(C[r] + EXPC);
    }
  }
  #pragma unroll
  for (int off = 1; off < 16; off <<= 1)
    #pragma unroll
    for (int r = 0; r < 4; ++r) z[r] += __shfl_xor(z[r], off);
  if (l15 == 0) {
    #pragma unroll
    for (int r = 0; r < 4; ++r)
      zp[qtr * 32768 + bh * 1024 + n0 + lhi * 4 + r] = z[r];
  }
}

// --------------------------------------- merge 4 z-quarters -> invZ
__global__ __launch_bounds__(256) void k_zmerge(const float* __restrict__ zp,
                                                float* __restrict__ invZ)
{
  int idx = blockIdx.x * 256 + threadIdx.x;   // < 32768
  float z = zp[idx] + zp[32768 + idx] + zp[65536 + idx] + zp[98304 + idx];
  invZ[idx] = 1.f / z;
}

// ---------------- pass B: per block (b, ntile, mq).
// phase1: wave w owns the 32-m chunk w; computes all-head scores (swapped QK^T,
// permuted K rows), packs softmax'd P per head as bf16 PV-A-frags -> LDS.
// phase2: wave w = output head g; mixes the 8 per-head frags per m-chunk with
// cm8[8] regs, BN stats for its g, PV MFMA. No big register arrays anywhere.
__global__ __launch_bounds__(512, 4) void k_passB(
    const u16* __restrict__ qhi, const u16* __restrict__ qlo,
    const u16* __restrict__ khi, const u16* __restrict__ klo,
    const u16* __restrict__ vtr, const float* __restrict__ invZ,
    const float* __restrict__ rw,
    float* __restrict__ U0, float* __restrict__ U1,
    float* __restrict__ U2, float* __restrict__ U3,
    float* __restrict__ pstat)
{
  __shared__ u16 plds[32768];    // 64KB: [mchunk(8)][h(8)][lane(64)] bf16x8
  int bid = blockIdx.x;          // b*256 + nt*4 + mq
  int b = bid >> 8, rest = bid & 255, nt = rest >> 2, mq = rest & 3;
  int n0 = nt * 16;
  int t = threadIdx.x, lane = t & 63, w = t >> 6;
  int l15 = lane & 15, lhi = lane >> 4;
  int mbase = mq * 256 + w * 32;                       // phase-1 m chunk
  int mrow0 = mbase + ((l15 >> 2) * 8) + (l15 & 3);    // permuted K row, tile0

  // ---- phase 1: per-head P frags to LDS
  #pragma unroll 1
  for (int h = 0; h < 8; ++h) {
    size_t base = (size_t)(b * 8 + h) * 1024;
    const u16* qhp = qhi + (base + n0 + l15) * 96 + lhi * 8;
    const u16* qlp = qlo + (base + n0 + l15) * 96 + lhi * 8;
    const u16* khp = khi + (base + mrow0) * 96 + lhi * 8;
    const u16* klp = klo + (base + mrow0) * 96 + lhi * 8;
    f32x4 C0 = {0.f, 0.f, 0.f, 0.f}, C1 = {0.f, 0.f, 0.f, 0.f};
    #pragma unroll
    for (int kk = 0; kk < 3; ++kk) {
      bf16x8 qh8 = *(const bf16x8*)(qhp + kk * 32);
      bf16x8 ql8 = *(const bf16x8*)(qlp + kk * 32);
      bf16x8 kh0 = *(const bf16x8*)(khp + kk * 32);
      bf16x8 kl0 = *(const bf16x8*)(klp + kk * 32);
      bf16x8 kh1 = *(const bf16x8*)(khp + 384 + kk * 32);  // +4 rows
      bf16x8 kl1 = *(const bf16x8*)(klp + 384 + kk * 32);
      C0 = mfma16(kh0, qh8, C0);   // q_hi*k_hi
      C0 = mfma16(kl0, qh8, C0);   // q_hi*k_lo
      C0 = mfma16(kh0, ql8, C0);   // q_lo*k_hi
      C1 = mfma16(kh1, qh8, C1);
      C1 = mfma16(kl1, qh8, C1);
      C1 = mfma16(kh1, ql8, C1);
    }
    float iz = invZ[base + n0 + l15];
    union { u16 us[8]; bf16x8 bv; } pk;
    #pragma unroll
    for (int r = 0; r < 4; ++r) {
      pk.us[r]     = f2bf(exp2f(C0[r] + EXPC) * iz);   // m-off = lhi*8 + r
      pk.us[4 + r] = f2bf(exp2f(C1[r] + EXPC) * iz);   // m-off = lhi*8 + 4 + r
    }
    *(bf16x8*)&plds[((w * 8 + h) * 64 + lane) * 8] = pk.bv;
  }
  __syncthreads();

  // ---- phase 2: wave w = output head g
  float wg[8];
  #pragma unroll
  for (int h = 0; h < 8; ++h) wg[h] = rw[w * 8 + h];
  float cg = -(((wg[0] + wg[1]) + (wg[2] + wg[3])) +
               ((wg[4] + wg[5]) + (wg[6] + wg[7]))) * (1.f / 1024.f);
  f32x4 acc[6];
  #pragma unroll
  for (int ds = 0; ds < 6; ++ds) acc[ds] = (f32x4){0.f, 0.f, 0.f, 0.f};
  float sc = 0.f, scc = 0.f;
  size_t vbase = (size_t)(b * 8 + w) * 96;
  #pragma unroll 1
  for (int mc = 0; mc < 8; ++mc) {
    float cm8[8];
    #pragma unroll
    for (int jj = 0; jj < 8; ++jj) cm8[jj] = cg;
    #pragma unroll
    for (int h = 0; h < 8; ++h) {
      union { u32 ud[4]; bf16x8 bv; } pf;
      pf.bv = *(const bf16x8*)&plds[((mc * 8 + h) * 64 + lane) * 8];
      float wgh = wg[h];
      #pragma unroll
      for (int k2 = 0; k2 < 4; ++k2) {
        union { u32 u; float f; } lo, hi;
        lo.u = pf.ud[k2] << 16;
        hi.u = pf.ud[k2] & 0xffff0000u;
        cm8[2 * k2]     += wgh * lo.f;
        cm8[2 * k2 + 1] += wgh * hi.f;
      }
    }
    union { u16 us[8]; bf16x8 bv; } pk;
    #pragma unroll
    for (int jj = 0; jj < 8; ++jj) {
      sc += cm8[jj]; scc += cm8[jj] * cm8[jj];
      pk.us[jj] = f2bf(cm8[jj]);
    }
    int mof = mq * 256 + mc * 32 + lhi * 8;
    #pragma unroll
    for (int ds = 0; ds < 6; ++ds) {
      bf16x8 vf = *(const bf16x8*)(vtr + (vbase + ds * 16 + l15) * 1024 + mof);
      acc[ds] = mfma16(pk.bv, vf, acc[ds]);
    }
  }
  // BN stat partials: one row per block, wave g fills cols g and 8+g
  #pragma unroll
  for (int off = 32; off > 0; off >>= 1) {
    sc += __shfl_down(sc, off); scc += __shfl_down(scc, off);
  }
  if (lane == 0) { pstat[bid * 16 + w] = sc; pstat[bid * 16 + 8 + w] = scc; }

  float* Uq = (mq == 0) ? U0 : (mq == 1) ? U1 : (mq == 2) ? U2 : U3;
  #pragma unroll
  for (int ds = 0; ds < 6; ++ds)
    #pragma unroll
    for (int r = 0; r < 4; ++r) {
      int n = lhi * 4 + r;
      Uq[((size_t)(b * 1024 + n0 + n)) * 768 + w * 96 + ds * 16 + l15] = acc[ds][r];
    }
}

// ------------------------------------------------- colsum(V) per (b,h,d), fp32
__global__ __launch_bounds__(384) void k_vcs(const float* __restrict__ vb,
                                             float* __restrict__ vcs)
{
  __shared__ float part[4][96];
  int bh = blockIdx.x, t = threadIdx.x;
  int c = t % 96, g4 = t / 96;
  float a = 0.f;
  const float* vp = vb + (size_t)bh * 98304 + (size_t)g4 * 24576 + c;
  for (int m = 0; m < 256; ++m) a += vp[m * 96];
  part[g4][c] = a;
  __syncthreads();
  if (t < 96) vcs[bh * 96 + t] = part[0][t] + part[1][t] + part[2][t] + part[3][t];
}

// ---------------- BN partial reduce stage 1: 64 blocks x 16 rows -> [64][16]
__global__ __launch_bounds__(256) void k_statred1(const float* __restrict__ pstat,
                                                  float* __restrict__ pred)
{
  __shared__ float part[16][17];
  int bb = blockIdx.x, t = threadIdx.x;
  int j = t >> 4, s = t & 15;
  part[j][s] = pstat[(size_t)(bb * 16 + s) * 16 + j];
  __syncthreads();
  if (t < 16) {
    float v = 0.f;
    #pragma unroll
    for (int s2 = 0; s2 < 16; ++s2) v += part[t][s2];
    pred[bb * 16 + t] = v;
  }
}

// ---------------- BN partial reduce stage 2: [64][16] -> stats[16]
__global__ __launch_bounds__(256) void k_statred2(const float* __restrict__ pred,
                                                  float* __restrict__ stats)
{
  __shared__ float part[16][17];
  int t = threadIdx.x;
  int j = t >> 4, s = t & 15;
  float a = 0.f;
  #pragma unroll
  for (int k2 = 0; k2 < 4; ++k2)
    a += pred[(size_t)(s + 16 * k2) * 16 + j];
  part[j][s] = a;
  __syncthreads();
  if (t < 16) {
    float v = 0.f;
    #pragma unroll
    for (int s2 = 0; s2 < 16; ++s2) v += part[t][s2];
    stats[t] = v;
  }
}

// ------------- BN affine: ubb = bf16(sg*(U0+U1+U2+U3) + (bnb - sg*mc)*colsum(V))
__global__ __launch_bounds__(256) void k_bnfin(const float* __restrict__ U0,
    const float* __restrict__ U1, const float* __restrict__ U2,
    const float* __restrict__ U3, const float* __restrict__ vcs,
    const float* __restrict__ stats, const float* __restrict__ bng,
    const float* __restrict__ bnb, u16* __restrict__ ubb)
{
  size_t idx = (size_t)blockIdx.x * 256 + threadIdx.x;
  int col = (int)(idx % 768); int i = (int)(idx / 768); int b = i >> 10;
  int g = col / 96, d = col - g * 96;
  const float cnt = 4194304.f;  // B*N*N
  float mc = stats[g] / cnt;
  float var = stats[8 + g] / cnt - mc * mc;
  float sg = bng[g] * rsqrtf(var + EPSV);
  float tg = bnb[g] - sg * mc;
  float u = (U0[idx] + U1[idx]) + (U2[idx] + U3[idx]);
  ubb[idx] = f2bf(sg * u + tg * vcs[(b * 8 + g) * 96 + d]);
}

// -------- bf16 MFMA GEMM: out = A[M,K]@W[N,K]^T + bias (+res)(+gelu)(+LN stats)
template<int GELU_, int RES_, int STATS_, int BF16OUT>
__global__ __launch_bounds__(256) void k_gemm(
    const u16* __restrict__ A, const u16* __restrict__ W,
    const float* __restrict__ bias, const float* __restrict__ res,
    float* __restrict__ out, u16* __restrict__ outb,
    int K, int Nc, float* __restrict__ stats)
{
  __shared__ u16 As[8192], Bs[8192];   // 128 rows x 64 cols, XOR-swizzled
  __shared__ float red[8];
  int t = threadIdx.x, lane = t & 63, wv = t >> 6;
  int l15 = lane & 15, lhi = lane >> 4;
  int i0 = blockIdx.y * 128, j0 = blockIdx.x * 128;
  int wr = wv >> 1, wc = wv & 1;
  f32x4 acc[4][4];
  #pragma unroll
  for (int mi = 0; mi < 4; ++mi)
    #pragma unroll
    for (int ni = 0; ni < 4; ++ni) acc[mi][ni] = (f32x4){0.f, 0.f, 0.f, 0.f};
  int rA = lane >> 3;
  int colel = 8 * ((lane & 7) ^ rA);   // pre-swizzled global source column
  for (int k0 = 0; k0 < K; k0 += 64) {
    if (k0) __syncthreads();
    #pragma unroll
    for (int i = 0; i < 4; ++i) {
      int cA = wv * 4 + i;
      int r = cA * 8 + rA;
      gload16(A + (size_t)(i0 + r) * K + k0 + colel, &As[cA * 512]);
      gload16(W + (size_t)(j0 + r) * K + k0 + colel, &Bs[cA * 512]);
    }
    __syncthreads();
    #pragma unroll
    for (int ks = 0; ks < 2; ++ks) {
      bf16x8 af[4], bf[4];
      #pragma unroll
      for (int mi = 0; mi < 4; ++mi) {
        int r2 = wr * 64 + mi * 16 + l15;
        af[mi] = *(const bf16x8*)&As[r2 * 64 + ((ks * 32 + lhi * 8) ^ (8 * (r2 & 7)))];
      }
      #pragma unroll
      for (int ni = 0; ni < 4; ++ni) {
        int r3 = wc * 64 + ni * 16 + l15;
        bf[ni] = *(const bf16x8*)&Bs[r3 * 64 + ((ks * 32 + lhi * 8) ^ (8 * (r3 & 7)))];
      }
      #pragma unroll
      for (int mi = 0; mi < 4; ++mi)
        #pragma unroll
        for (int ni = 0; ni < 4; ++ni)
          acc[mi][ni] = mfma16(af[mi], bf[ni], acc[mi][ni]);
    }
  }
  float ls = 0.f, lss = 0.f;
  #pragma unroll
  for (int mi = 0; mi < 4; ++mi) {
    #pragma unroll
    for (int ni = 0; ni < 4; ++ni) {
      int col = j0 + wc * 64 + ni * 16 + l15;
      float bv = bias[col];
      #pragma unroll
      for (int r = 0; r < 4; ++r) {
        int row = i0 + wr * 64 + mi * 16 + lhi * 4 + r;
        float val = acc[mi][ni][r] + bv;
        if (RES_) val += res[(size_t)row * Nc + col];
        if (GELU_) val = 0.5f * val * (1.f + erff(val * 0.70710678118654752f));
        if (BF16OUT) outb[(size_t)row * Nc + col] = f2bf(val);
        else out[(size_t)row * Nc + col] = val;
        if (STATS_) { ls += val; lss += val * val; }
      }
    }
  }
  if (STATS_) {
    #pragma unroll
    for (int off = 32; off > 0; off >>= 1) {
      ls += __shfl_down(ls, off); lss += __shfl_down(lss, off);
    }
    if (lane == 0) { red[wv * 2] = ls; red[wv * 2 + 1] = lss; }
    __syncthreads();
    if (t == 0) {
      int b = i0 >> 10;
      atomicAdd(&stats[b * 2],     red[0] + red[2] + red[4] + red[6]);
      atomicAdd(&stats[b * 2 + 1], red[1] + red[3] + red[5] + red[7]);
    }
  }
}

// ------------------------------- joint (N,D) LayerNorm apply (per-b scalars)
template<int BF16OUT>
__global__ __launch_bounds__(256) void k_ln(const float* __restrict__ y,
    const float* __restrict__ stats, const float* __restrict__ g,
    const float* __restrict__ bta, float* __restrict__ outp, u16* __restrict__ outb)
{
  size_t idx = (size_t)blockIdx.x * 256 + threadIdx.x;
  int i = (int)(idx / 768), col = (int)(idx % 768);
  int b = i >> 10, n = i & 1023;
  const float cnt = 786432.f;  // N*D
  float mu = stats[b * 2] / cnt;
  float var = stats[b * 2 + 1] / cnt - mu * mu;
  float r = rsqrtf(var + EPSV);
  size_t gi = (size_t)n * 768 + col;
  float v = (y[idx] - mu) * r * g[gi] + bta[gi];
  outp[idx] = v;
  if (BF16OUT) outb[idx] = f2bf(v);
}

extern "C" void kernel_launch(void* const* d_in, const int* in_sizes, int n_in,
                              void* d_out, int out_size, void* d_ws, size_t ws_size,
                              hipStream_t stream)
{
  const float* x   = (const float*)d_in[0];
  const float* qw  = (const float*)d_in[1];
  const float* kw  = (const float*)d_in[2];
  const float* vw  = (const float*)d_in[3];
  const float* rw  = (const float*)d_in[4];
  const float* bng = (const float*)d_in[6];
  const float* bnb = (const float*)d_in[7];
  const float* pw  = (const float*)d_in[8];
  const float* pb  = (const float*)d_in[9];
  const float* lng = (const float*)d_in[10];
  const float* lnb = (const float*)d_in[11];
  const float* fw1 = (const float*)d_in[12];
  const float* fb1 = (const float*)d_in[13];
  const float* fw2 = (const float*)d_in[14];
  const float* fb2 = (const float*)d_in[15];
  float* out = (float*)d_out;

  float* ws    = (float*)d_ws;
  float* stats = ws;                  // 64 ([0..15] BN, [16..23] LN1, [24..31] LN2)
  float* pstat = ws + 64;             // 16384 (1024 blocks x 16)
  float* vcs   = ws + 131136;         // 3072
  float* zp    = ws + 134208;         // 131072 (4 quarters x 32768)
  float* invZ  = ws + 265280;         // 32768
  float* vb    = ws + 298048;         // 3145728
  float* U0    = ws + 3443776;        // 3145728
  float* U1    = ws + 6589504;        // 3145728
  float* x1    = ws + 9735232;        // 3145728
  u16* u16b = (u16*)(ws + 12880960);
  u16* qhi  = u16b;
  u16* qlo  = u16b + 3145728;
  u16* khi  = u16b + 6291456;
  u16* klo  = u16b + 9437184;
  u16* vtr  = u16b + 12582912;
  u16* ubb  = u16b + 15728640;
  u16* pwb  = u16b + 18874368;
  u16* fw1b = u16b + 19464192;
  u16* fw2b = u16b + 21823488;        // ends 24182784 u16 (~100 MB total)
  float* U2 = vb;                     // vb dead after k_vtr/k_vcs
  float* U3 = x1;                     // x1 written only later by k_ln
  float* pred = zp;                   // zp dead after k_zmerge (1024 floats)
  u16* x1b = qhi;                     // attention u16 dead after passB
  u16* hb  = qlo;                     // spans qlo..vtr
  float* y1 = U0;
  float* y2 = vb;

  hipMemsetAsync(stats, 0, 64 * sizeof(float), stream);
  k_f2b<<<1024, 256, 0, stream>>>(pw, pwb, 589824);
  k_f2b<<<2048, 256, 0, stream>>>(fw1, fw1b, 2359296);
  k_f2b<<<2048, 256, 0, stream>>>(fw2, fw2b, 2359296);

  k_conv<<<4096, 256, 0, stream>>>(x, qw, kw, vw, qhi, qlo, khi, klo, vb);
  k_passA<<<2048, 256, 0, stream>>>(qhi, qlo, khi, klo, zp);
  k_vtr<<<256, 256, 0, stream>>>(vb, vtr);
  k_vcs<<<32, 384, 0, stream>>>(vb, vcs);
  k_zmerge<<<128, 256, 0, stream>>>(zp, invZ);
  k_passB<<<1024, 512, 0, stream>>>(qhi, qlo, khi, klo, vtr, invZ, rw,
                                    U0, U1, U2, U3, pstat);
  k_statred1<<<64, 256, 0, stream>>>(pstat, pred);
  k_statred2<<<1, 256, 0, stream>>>(pred, stats);
  k_bnfin<<<12288, 256, 0, stream>>>(U0, U1, U2, U3, vcs, stats, bng, bnb, ubb);

  k_gemm<0,1,1,0><<<dim3(6, 32), 256, 0, stream>>>(ubb, pwb, pb, x, y1, nullptr, 768, 768, stats + 16);
  k_ln<1><<<12288, 256, 0, stream>>>(y1, stats + 16, lng, lnb, x1, x1b);
  k_gemm<1,0,0,1><<<dim3(24, 32), 256, 0, stream>>>(x1b, fw1b, fb1, nullptr, nullptr, hb, 768, 3072, nullptr);
  k_gemm<0,1,1,0><<<dim3(6, 32), 256, 0, stream>>>(hb, fw2b, fb2, x1, y2, nullptr, 3072, 768, stats + 24);
  k_ln<0><<<12288, 256, 0, stream>>>(y2, stats + 24, lng, lnb, out, nullptr);
}